// Round 11
// baseline (117.075 us; speedup 1.0000x reference)
//
#include <hip/hip_runtime.h>
#include <hip/hip_bf16.h>

#define N_NODES 65536
#define NUM_G   64
#define GSIZE   1024
#define DIM     64

using frag_ab = __attribute__((ext_vector_type(8))) short;   // 8 bf16 (4 VGPRs)
using f32x4   = __attribute__((ext_vector_type(4))) float;   // 4 fp32 accum

__device__ __forceinline__ unsigned short f2bf(float x) {
    union { float f; unsigned int u; } v; v.f = x;
    unsigned int r = v.u + 0x7FFFu + ((v.u >> 16) & 1u);   // RNE
    return (unsigned short)(r >> 16);
}

// Kernel 1: fp32 row-normalize z1,z2 -> bf16 copies (graph stride gs ushorts,
// padded to break L2 channel congruence); pos = (z1n . z2n) * inv_t (fp32).
__global__ __launch_bounds__(256) void normalize_k(
    const float* __restrict__ z1, const float* __restrict__ z2,
    unsigned short* __restrict__ z1n, unsigned short* __restrict__ z2n,
    float* __restrict__ pos, int gs)
{
    int tid = threadIdx.x;
    int row = blockIdx.x * 16 + (tid >> 4);
    int l4  = tid & 15;
    float4 v1 = *((const float4*)(z1 + (size_t)row * DIM) + l4);
    float4 v2 = *((const float4*)(z2 + (size_t)row * DIM) + l4);
    float ss1 = v1.x*v1.x + v1.y*v1.y + v1.z*v1.z + v1.w*v1.w;
    float ss2 = v2.x*v2.x + v2.y*v2.y + v2.z*v2.z + v2.w*v2.w;
    float dt  = v1.x*v2.x + v1.y*v2.y + v1.z*v2.z + v1.w*v2.w;
    #pragma unroll
    for (int m = 1; m < 16; m <<= 1) {
        ss1 += __shfl_xor(ss1, m);
        ss2 += __shfl_xor(ss2, m);
        dt  += __shfl_xor(dt,  m);
    }
    float in1 = 1.0f / sqrtf(ss1);
    float in2 = 1.0f / sqrtf(ss2);
    ushort4 o1, o2;
    o1.x = f2bf(v1.x*in1); o1.y = f2bf(v1.y*in1); o1.z = f2bf(v1.z*in1); o1.w = f2bf(v1.w*in1);
    o2.x = f2bf(v2.x*in2); o2.y = f2bf(v2.y*in2); o2.z = f2bf(v2.z*in2); o2.w = f2bf(v2.w*in2);
    int g = row >> 10, r = row & 1023;
    size_t base = (size_t)g * gs + (size_t)r * DIM;
    *((ushort4*)(z1n + base) + l4) = o1;
    *((ushort4*)(z2n + base) + l4) = o2;
    if (l4 == 0) pos[row] = dt * in1 * in2 * 2.0f;   // inv_t = 2
}

// Kernel 2, MODE 0 (real): R6 base + DE-CONGRUENCE: padded graph stride and
// per-wave rotated tile-sweep start so concurrent waves hit different L2
// channel offsets (R9 analysis: invariant ~28us stall = address-congruence
// queuing, the only property shared by every prior structure).
// MODE 1 (ablation x2 sweeps): B-loads from a fixed 4KB L1-resident window
// (opaque VGPR pointer defeats LICM); isolates the load path at L1-hit speed.
template <int MODE>
__global__ __launch_bounds__(256, 4) void grace_main_k(
    const unsigned short* __restrict__ z1n,
    const unsigned short* __restrict__ z2n,
    const float* __restrict__ pos,
    float* __restrict__ partials, int gs, int sweeps)
{
    __shared__ float sums[4][64];   // per-wave partial row sums
    __shared__ float red[4];

    int tid = threadIdx.x;
    int n = blockIdx.x;
    int g = (n & 7) + 8 * (n >> 7);   // all 16 blocks of a graph share XCD (n%8 model)
    int stripe = (n >> 3) & 15;
    int w = tid >> 6, l = tid & 63;
    const unsigned short* z1g = z1n + (size_t)g * gs;
    const unsigned short* z2g = z2n + (size_t)g * gs;
    int rowBase = stripe * 64;

    // A fragments: 64 rows, 4 tiles x 2 K-halves. row = rowBase + rt*16 + (l&15)
    int ar = l & 15, ak = (l >> 4) * 8;
    frag_ab A[4][2];
    #pragma unroll
    for (int rt = 0; rt < 4; ++rt) {
        const unsigned short* p = z1g + (rowBase + rt * 16 + ar) * DIM + ak;
        A[rt][0] = *(const frag_ab*)(p);
        A[rt][1] = *(const frag_ab*)(p + 32);
    }

    float expacc[4][4] = {};   // static indexing only

    // Column stream: wave w covers virtual cols [w*512, w*512+512) of [z2 | z1].
    const unsigned short* sb0 =
        ((w < 2) ? z2g : z1g) + (((w & 1) * 512 + ar) * DIM + ak);

    const float K1 = 2.8853900817779268f;   // 2 * log2(e)   (inv_t=2 folded)
    const float K0 = -2.8853900817779268f;  // -2 * log2(e)  (fixed shift m=2)

    auto compute = [&](frag_ab b0, frag_ab b1) {
        f32x4 z = {0.f, 0.f, 0.f, 0.f};
        f32x4 c0 = __builtin_amdgcn_mfma_f32_16x16x32_bf16(A[0][0], b0, z, 0, 0, 0);
        f32x4 c1 = __builtin_amdgcn_mfma_f32_16x16x32_bf16(A[1][0], b0, z, 0, 0, 0);
        f32x4 c2 = __builtin_amdgcn_mfma_f32_16x16x32_bf16(A[2][0], b0, z, 0, 0, 0);
        f32x4 c3 = __builtin_amdgcn_mfma_f32_16x16x32_bf16(A[3][0], b0, z, 0, 0, 0);
        c0 = __builtin_amdgcn_mfma_f32_16x16x32_bf16(A[0][1], b1, c0, 0, 0, 0);
        c1 = __builtin_amdgcn_mfma_f32_16x16x32_bf16(A[1][1], b1, c1, 0, 0, 0);
        c2 = __builtin_amdgcn_mfma_f32_16x16x32_bf16(A[2][1], b1, c2, 0, 0, 0);
        c3 = __builtin_amdgcn_mfma_f32_16x16x32_bf16(A[3][1], b1, c3, 0, 0, 0);
        #pragma unroll
        for (int r = 0; r < 4; ++r) {
            expacc[0][r] += __builtin_amdgcn_exp2f(fmaf(c0[r], K1, K0));
            expacc[1][r] += __builtin_amdgcn_exp2f(fmaf(c1[r], K1, K0));
            expacc[2][r] += __builtin_amdgcn_exp2f(fmaf(c2[r], K1, K0));
            expacc[3][r] += __builtin_amdgcn_exp2f(fmaf(c3[r], K1, K0));
        }
    };

    if constexpr (MODE == 0) {
        // rotated sweep: tile visit order (t + rot) & 31, bijective
        int rot = (n * 5 + w * 9) & 31;
        auto tptr = [&](int t) -> const unsigned short* {
            return sb0 + (size_t)(((t + rot) & 31) * (16 * DIM));
        };
        frag_ab bA0 = *(const frag_ab*)(tptr(0));
        frag_ab bA1 = *(const frag_ab*)(tptr(0) + 32);
        #pragma unroll 1
        for (int t = 0; t < 32; t += 2) {
            frag_ab bB0 = *(const frag_ab*)(tptr(t + 1));
            frag_ab bB1 = *(const frag_ab*)(tptr(t + 1) + 32);
            compute(bA0, bA1);
            if (t < 30) {
                bA0 = *(const frag_ab*)(tptr(t + 2));
                bA1 = *(const frag_ab*)(tptr(t + 2) + 32);
            }
            compute(bB0, bB1);
        }
    } else {
        // ABLATION: same load/MFMA/accumulate counts, B from fixed 4KB window.
        // "+v" keeps the pointer opaque in VGPRs (the "+s" variant failed to
        // compile: pointer is divergent-by-construction -> no SGPR copy).
        #pragma unroll 1
        for (int s = 0; s < sweeps; ++s) {
            const unsigned short* sb = sb0;
            #pragma unroll 1
            for (int t = 0; t < 32; t += 2) {
                asm volatile("" : "+v"(sb));   // opaque: defeats LICM/CSE
                frag_ab bA0 = *(const frag_ab*)(sb);
                frag_ab bA1 = *(const frag_ab*)(sb + 32);
                frag_ab bB0 = *(const frag_ab*)(sb + 16 * DIM);
                frag_ab bB1 = *(const frag_ab*)(sb + 16 * DIM + 32);
                compute(bA0, bA1);
                compute(bB0, bB1);
            }
        }
    }

    // Reduce C cols (low-4 lane bits); C/D layout: row = (l>>4)*4 + r, col = l&15.
    #pragma unroll
    for (int rt = 0; rt < 4; ++rt) {
        #pragma unroll
        for (int r = 0; r < 4; ++r) {
            float s = expacc[rt][r];
            s += __shfl_xor(s, 1); s += __shfl_xor(s, 2);
            s += __shfl_xor(s, 4); s += __shfl_xor(s, 8);
            if ((l & 15) == 0) sums[w][rt * 16 + (l >> 4) * 4 + r] = s;
        }
    }
    __syncthreads();

    float term = 0.f;
    if (tid < 64) {
        float S = sums[0][tid] + sums[1][tid] + sums[2][tid] + sums[3][tid];
        if constexpr (MODE == 0) {
            // shift m=2; sim11 diag contributes exp(0)=1, excluded in closed form
            term = 2.0f + __logf(S - 1.0f) - pos[g * GSIZE + rowBase + tid];
        } else {
            term = S;   // raw sums to scratch
        }
    }
    #pragma unroll
    for (int m = 1; m < 64; m <<= 1) term += __shfl_xor(term, m);
    if (l == 0) red[w] = term;
    __syncthreads();
    if (tid == 0) partials[n] = red[0] + red[1] + red[2] + red[3];
}

// Kernel 3: deterministic 1024 -> 1 reduce, mean over nodes.
__global__ __launch_bounds__(256) void final_reduce_k(
    const float* __restrict__ partials, float* __restrict__ out)
{
    int tid = threadIdx.x;
    float s = partials[tid] + partials[tid + 256] + partials[tid + 512] + partials[tid + 768];
    #pragma unroll
    for (int m = 1; m < 64; m <<= 1) s += __shfl_xor(s, m);
    __shared__ float red[4];
    if ((tid & 63) == 0) red[tid >> 6] = s;
    __syncthreads();
    if (tid == 0) out[0] = (red[0] + red[1] + red[2] + red[3]) * (1.0f / N_NODES);
}

extern "C" void kernel_launch(void* const* d_in, const int* in_sizes, int n_in,
                              void* d_out, int out_size, void* d_ws, size_t ws_size,
                              hipStream_t stream)
{
    const float* z1 = (const float*)d_in[0];
    const float* z2 = (const float*)d_in[1];
    char* ws = (char*)d_ws;

    // Padded per-graph stride (ushorts): +128 ushorts = +256B breaks the
    // power-of-2 congruence of graph bases. Fallback to tight layout if ws small.
    int gs = GSIZE * DIM + 128;                     // 131200
    size_t arr = (size_t)NUM_G * gs * 2;            // bytes per bf16 array
    size_t need = 2 * arr + 262144 + 8192;
    if (ws_size < need) { gs = GSIZE * DIM; arr = (size_t)NUM_G * gs * 2; }

    unsigned short* z1n = (unsigned short*)ws;
    unsigned short* z2n = (unsigned short*)(ws + arr);
    float* pos          = (float*)(ws + 2 * arr);
    float* partials     = (float*)(ws + 2 * arr + 262144);

    normalize_k<<<dim3(N_NODES / 16), dim3(256), 0, stream>>>(z1, z2, z1n, z2n, pos, gs);
    // Real computation (de-congruenced).
    grace_main_k<0><<<dim3(NUM_G * 16), dim3(256), 0, stream>>>(z1n, z2n, pos, partials, gs, 1);
    // ABLATION (this round): L1-window loads, 2x sweeps, raw sums into pos as
    // scratch (pos already consumed by MODE0; rewritten by normalize_k each replay).
    grace_main_k<1><<<dim3(NUM_G * 16), dim3(256), 0, stream>>>(z1n, z2n, pos, pos, gs, 2);
    final_reduce_k<<<dim3(1), dim3(256), 0, stream>>>(partials, (float*)d_out);
}

// Round 12
// 77.832 us; speedup vs baseline: 1.5042x; 1.5042x over previous
//
#include <hip/hip_runtime.h>
#include <hip/hip_bf16.h>

#define N_NODES 65536
#define NUM_G   64
#define GSIZE   1024
#define DIM     64

using frag_ab = __attribute__((ext_vector_type(8))) short;   // 8 bf16 (4 VGPRs)
using f32x4   = __attribute__((ext_vector_type(4))) float;   // 4 fp32 accum

__device__ __forceinline__ unsigned short f2bf(float x) {
    union { float f; unsigned int u; } v; v.f = x;
    unsigned int r = v.u + 0x7FFFu + ((v.u >> 16) & 1u);   // RNE
    return (unsigned short)(r >> 16);
}

// Kernel 1: fp32 row-normalize z1,z2 -> bf16 copies (padded graph stride gs);
// pos = (z1n . z2n) * inv_t (fp32).
__global__ __launch_bounds__(256) void normalize_k(
    const float* __restrict__ z1, const float* __restrict__ z2,
    unsigned short* __restrict__ z1n, unsigned short* __restrict__ z2n,
    float* __restrict__ pos, int gs)
{
    int tid = threadIdx.x;
    int row = blockIdx.x * 16 + (tid >> 4);
    int l4  = tid & 15;
    float4 v1 = *((const float4*)(z1 + (size_t)row * DIM) + l4);
    float4 v2 = *((const float4*)(z2 + (size_t)row * DIM) + l4);
    float ss1 = v1.x*v1.x + v1.y*v1.y + v1.z*v1.z + v1.w*v1.w;
    float ss2 = v2.x*v2.x + v2.y*v2.y + v2.z*v2.z + v2.w*v2.w;
    float dt  = v1.x*v2.x + v1.y*v2.y + v1.z*v2.z + v1.w*v2.w;
    #pragma unroll
    for (int m = 1; m < 16; m <<= 1) {
        ss1 += __shfl_xor(ss1, m);
        ss2 += __shfl_xor(ss2, m);
        dt  += __shfl_xor(dt,  m);
    }
    float in1 = 1.0f / sqrtf(ss1);
    float in2 = 1.0f / sqrtf(ss2);
    ushort4 o1, o2;
    o1.x = f2bf(v1.x*in1); o1.y = f2bf(v1.y*in1); o1.z = f2bf(v1.z*in1); o1.w = f2bf(v1.w*in1);
    o2.x = f2bf(v2.x*in2); o2.y = f2bf(v2.y*in2); o2.z = f2bf(v2.z*in2); o2.w = f2bf(v2.w*in2);
    int g = row >> 10, r = row & 1023;
    size_t base = (size_t)g * gs + (size_t)r * DIM;
    *((ushort4*)(z1n + base) + l4) = o1;
    *((ushort4*)(z2n + base) + l4) = o2;
    if (l4 == 0) pos[row] = dt * in1 * in2 * 2.0f;   // inv_t = 2
}

// Kernel 2: PIPE-OVERLAP version. R11 showed both pipes run at demanded duty
// (VALU ~11us, MFMA ~8us per sweep) but don't overlap: homogeneous waves
// alternate [MFMA-burst -> exp-burst] in lockstep at only 4 waves/SIMD.
// Fix: 8 waves/SIMD (grid 2048 = 64 graphs x 32 stripes of 32 rows, rt=2,
// VGPR-capped via launch_bounds(256,8)) + per-wave rotated sweep start so
// co-resident waves sit in different phases. Padded stride + XCD clustering
// + 2-deep prefetch retained. No LDS staging, no main-loop barriers.
__global__ __launch_bounds__(256, 8) void grace_main_k(
    const unsigned short* __restrict__ z1n,
    const unsigned short* __restrict__ z2n,
    const float* __restrict__ pos,
    float* __restrict__ partials, int gs)
{
    __shared__ float sums[4][32];   // per-wave partial row sums
    __shared__ float red[4];

    int tid = threadIdx.x;
    int n = blockIdx.x;
    int g = (n & 7) + 8 * (n >> 8);   // all 32 blocks of a graph share XCD (n%8 model)
    int stripe = (n >> 3) & 31;
    int w = tid >> 6, l = tid & 63;
    const unsigned short* z1g = z1n + (size_t)g * gs;
    const unsigned short* z2g = z2n + (size_t)g * gs;
    int rowBase = stripe * 32;

    // A fragments: 32 rows, 2 tiles x 2 K-halves. row = rowBase + rt*16 + (l&15)
    int ar = l & 15, ak = (l >> 4) * 8;
    frag_ab A[2][2];
    #pragma unroll
    for (int rt = 0; rt < 2; ++rt) {
        const unsigned short* p = z1g + (rowBase + rt * 16 + ar) * DIM + ak;
        A[rt][0] = *(const frag_ab*)(p);
        A[rt][1] = *(const frag_ab*)(p + 32);
    }

    float expacc[2][4] = {};   // static indexing only

    // Column stream: wave w covers virtual cols [w*512, w*512+512) of [z2 | z1].
    const unsigned short* sb0 =
        ((w < 2) ? z2g : z1g) + (((w & 1) * 512 + ar) * DIM + ak);

    const float K1 = 2.8853900817779268f;   // 2 * log2(e)   (inv_t=2 folded)
    const float K0 = -2.8853900817779268f;  // -2 * log2(e)  (fixed shift m=2)

    auto compute = [&](frag_ab b0, frag_ab b1) {
        f32x4 z = {0.f, 0.f, 0.f, 0.f};
        f32x4 c0 = __builtin_amdgcn_mfma_f32_16x16x32_bf16(A[0][0], b0, z, 0, 0, 0);
        f32x4 c1 = __builtin_amdgcn_mfma_f32_16x16x32_bf16(A[1][0], b0, z, 0, 0, 0);
        c0 = __builtin_amdgcn_mfma_f32_16x16x32_bf16(A[0][1], b1, c0, 0, 0, 0);
        c1 = __builtin_amdgcn_mfma_f32_16x16x32_bf16(A[1][1], b1, c1, 0, 0, 0);
        #pragma unroll
        for (int r = 0; r < 4; ++r) {
            expacc[0][r] += __builtin_amdgcn_exp2f(fmaf(c0[r], K1, K0));
            expacc[1][r] += __builtin_amdgcn_exp2f(fmaf(c1[r], K1, K0));
        }
    };

    // rotated sweep: tile visit order (t + rot) & 31 — staggers wave phases
    int rot = (n * 5 + w * 9) & 31;
    auto tptr = [&](int t) -> const unsigned short* {
        return sb0 + (size_t)(((t + rot) & 31) * (16 * DIM));
    };

    frag_ab bA0 = *(const frag_ab*)(tptr(0));
    frag_ab bA1 = *(const frag_ab*)(tptr(0) + 32);
    #pragma unroll 1
    for (int t = 0; t < 32; t += 2) {
        frag_ab bB0 = *(const frag_ab*)(tptr(t + 1));
        frag_ab bB1 = *(const frag_ab*)(tptr(t + 1) + 32);
        compute(bA0, bA1);
        if (t < 30) {
            bA0 = *(const frag_ab*)(tptr(t + 2));
            bA1 = *(const frag_ab*)(tptr(t + 2) + 32);
        }
        compute(bB0, bB1);
    }

    // Reduce C cols (low-4 lane bits); C/D layout: row = (l>>4)*4 + r, col = l&15.
    #pragma unroll
    for (int rt = 0; rt < 2; ++rt) {
        #pragma unroll
        for (int r = 0; r < 4; ++r) {
            float s = expacc[rt][r];
            s += __shfl_xor(s, 1); s += __shfl_xor(s, 2);
            s += __shfl_xor(s, 4); s += __shfl_xor(s, 8);
            if ((l & 15) == 0) sums[w][rt * 16 + (l >> 4) * 4 + r] = s;
        }
    }
    __syncthreads();

    float term = 0.f;
    if (tid < 32) {
        float S = sums[0][tid] + sums[1][tid] + sums[2][tid] + sums[3][tid];
        // shift m=2; sim11 diag contributes exp(0)=1, excluded in closed form
        term = 2.0f + __logf(S - 1.0f) - pos[g * GSIZE + rowBase + tid];
    }
    #pragma unroll
    for (int m = 1; m < 32; m <<= 1) term += __shfl_xor(term, m);
    if (tid == 0) partials[n] = term;
}

// Kernel 3: deterministic 2048 -> 1 reduce, mean over nodes.
__global__ __launch_bounds__(256) void final_reduce_k(
    const float* __restrict__ partials, float* __restrict__ out)
{
    int tid = threadIdx.x;
    float s = 0.f;
    #pragma unroll
    for (int k = 0; k < 8; ++k) s += partials[tid + k * 256];
    #pragma unroll
    for (int m = 1; m < 64; m <<= 1) s += __shfl_xor(s, m);
    __shared__ float red[4];
    if ((tid & 63) == 0) red[tid >> 6] = s;
    __syncthreads();
    if (tid == 0) out[0] = (red[0] + red[1] + red[2] + red[3]) * (1.0f / N_NODES);
}

extern "C" void kernel_launch(void* const* d_in, const int* in_sizes, int n_in,
                              void* d_out, int out_size, void* d_ws, size_t ws_size,
                              hipStream_t stream)
{
    const float* z1 = (const float*)d_in[0];
    const float* z2 = (const float*)d_in[1];
    char* ws = (char*)d_ws;

    // Padded per-graph stride (+256B) breaks power-of-2 congruence of graph bases.
    int gs = GSIZE * DIM + 128;                     // 131200 ushorts
    size_t arr = (size_t)NUM_G * gs * 2;            // bytes per bf16 array
    size_t need = 2 * arr + 262144 + 16384;
    if (ws_size < need) { gs = GSIZE * DIM; arr = (size_t)NUM_G * gs * 2; }

    unsigned short* z1n = (unsigned short*)ws;
    unsigned short* z2n = (unsigned short*)(ws + arr);
    float* pos          = (float*)(ws + 2 * arr);
    float* partials     = (float*)(ws + 2 * arr + 262144);

    normalize_k<<<dim3(N_NODES / 16), dim3(256), 0, stream>>>(z1, z2, z1n, z2n, pos, gs);
    grace_main_k<<<dim3(NUM_G * 32), dim3(256), 0, stream>>>(z1n, z2n, pos, partials, gs);
    final_reduce_k<<<dim3(1), dim3(256), 0, stream>>>(partials, (float*)d_out);
}